// Round 1
// baseline (2500.940 us; speedup 1.0000x reference)
//
#include <hip/hip_runtime.h>
#include <hip/hip_bf16.h>

#define BN_EPS 1e-5f

typedef __attribute__((ext_vector_type(8))) short bf16x8;
typedef __attribute__((ext_vector_type(4))) float f32x4;

__device__ __forceinline__ short f2b(float f) {
  __hip_bfloat16 h = __float2bfloat16(f);
  short s;
  __builtin_memcpy(&s, &h, 2);
  return s;
}

// ---------------- ws layout (bytes) ----------------
// [0,1024)      : float sums[256]   (sum[128], sumsq[128])  -- must be zeroed
// [1024,2048)   : float mean[128] @ idx 256, inv[128] @ idx 384
// [2048,2560)   : float b1[128]   @ idx 512
// [4096,36864)  : ushort w1b[128*128]  (w1 * inv, bf16)
// [36864,167936): ushort w2b[256*256]  (permuted+padded w2, bf16)

__global__ void k_stats(const float* __restrict__ agg, float* __restrict__ ws, int nelem) {
  __shared__ float red[512];
  int tid = threadIdx.x;
  int gid = blockIdx.x * blockDim.x + tid;
  int stride = gridDim.x * blockDim.x;   // multiple of 128
  float s = 0.f, s2 = 0.f;
  for (int i = gid; i < nelem; i += stride) {
    float v = agg[i];
    s += v;
    s2 += v * v;
  }
  red[tid] = s;
  red[256 + tid] = s2;
  __syncthreads();
  if (tid < 128) {
    // threads tid and tid+128 cover the same column (stride % 128 == 0)
    atomicAdd(&ws[tid], red[tid] + red[tid + 128]);
    atomicAdd(&ws[128 + tid], red[256 + tid] + red[256 + tid + 128]);
  }
}

__global__ void k_finalize(float* __restrict__ ws, float inv_n) {
  int c = threadIdx.x;  // 128 threads
  float mean = ws[c] * inv_n;
  float var = ws[128 + c] * inv_n - mean * mean;
  ws[256 + c] = mean;
  ws[384 + c] = 1.0f / sqrtf(var + BN_EPS);
}

__global__ void k_prep(const float* __restrict__ w1, const float* __restrict__ w2,
                       char* __restrict__ wsb) {
  float* wsf = (float*)wsb;
  unsigned short* w1b = (unsigned short*)(wsb + 4096);
  unsigned short* w2b = (unsigned short*)(wsb + 36864);
  int b = blockIdx.x, t = threadIdx.x;
  if (b < 256) {
    // w2b[g][k]: k<128 -> a-block (orig f = 127+k); 128<=k<255 -> h-block (f = k-128); else 0
    int g = b, k = t;
    float v = 0.f;
    if (g < 255) {
      if (k < 128)       v = w2[g * 255 + 127 + k];
      else if (k < 255)  v = w2[g * 255 + (k - 128)];
    }
    w2b[g * 256 + k] = (unsigned short)f2b(v);
  } else {
    int idx = (b - 256) * 256 + t;          // 0..16383
    int k = idx & 127;
    w1b[idx] = (unsigned short)f2b(w1[idx] * wsf[384 + k]);
    if (b == 256 && t < 128) {
      float s = 0.f;
      for (int k2 = 0; k2 < 128; k2++)
        s += wsf[256 + k2] * wsf[384 + k2] * w1[t * 128 + k2];
      wsf[512 + t] = s;
    }
  }
}

// Fragment layout (mfma_f32_16x16x32_bf16):
//   A: row = lane&15, k = (lane>>4)*8 + j   (8 contiguous bf16 / lane)
//   B: col = lane&15, k = (lane>>4)*8 + j
//   C/D: col = lane&15, row = (lane>>4)*4 + reg   [measured m89]
__global__ __launch_bounds__(256, 2) void k_main(
    const float* __restrict__ h, const float* __restrict__ agg,
    const char* __restrict__ wsb, float* __restrict__ out, int N, int ntiles) {
  __shared__ __align__(16) char lds[4][4096];  // per-wave 16x128 bf16, XOR-swizzled
  const unsigned short* w1b = (const unsigned short*)(wsb + 4096);
  const unsigned short* w2b = (const unsigned short*)(wsb + 36864);
  const float* b1 = (const float*)(wsb + 2048);

  int tid = threadIdx.x;
  int wid = tid >> 6, lane = tid & 63;
  int lrow = lane & 15;   // A-row / B-col / C-col within tile
  int lgrp = lane >> 4;   // 0..3
  char* my_lds = lds[wid];

  float b1v[8];
#pragma unroll
  for (int n = 0; n < 8; n++) b1v[n] = b1[n * 16 + lrow];

  for (int tile = blockIdx.x * 4 + wid; tile < ntiles; tile += gridDim.x * 4) {
    int rb = tile << 4;
    int r = rb + lrow;
    bool rok = r < N;
    int rc = rok ? r : 0;

    // ---- A1 fragments: raw agg -> bf16 (BN folded into w1b/b1) ----
    bf16x8 a1[4];
#pragma unroll
    for (int kk = 0; kk < 4; kk++) {
      int k0 = kk * 32 + lgrp * 8;
      f32x4 v0 = {0.f, 0.f, 0.f, 0.f}, v1 = {0.f, 0.f, 0.f, 0.f};
      if (rok) {
        const f32x4* p = (const f32x4*)(agg + (size_t)rc * 128 + k0);
        v0 = p[0];
        v1 = p[1];
      }
      bf16x8 f;
      f[0] = f2b(v0[0]); f[1] = f2b(v0[1]); f[2] = f2b(v0[2]); f[3] = f2b(v0[3]);
      f[4] = f2b(v1[0]); f[5] = f2b(v1[1]); f[6] = f2b(v1[2]); f[7] = f2b(v1[3]);
      a1[kk] = f;
    }

    // ---- GEMM1: a_tile[16][128] = agg @ w1s^T ----
    f32x4 acc1[8];
#pragma unroll
    for (int n = 0; n < 8; n++) acc1[n] = (f32x4){0.f, 0.f, 0.f, 0.f};
#pragma unroll
    for (int kk = 0; kk < 4; kk++) {
#pragma unroll
      for (int n = 0; n < 8; n++) {
        bf16x8 bf = *(const bf16x8*)(w1b + (n * 16 + lrow) * 128 + kk * 32 + lgrp * 8);
        acc1[n] = __builtin_amdgcn_mfma_f32_16x16x32_bf16(a1[kk], bf, acc1[n], 0, 0, 0);
      }
    }

    // ---- bias + relu, C-layout -> LDS (bf16, XOR swizzle vs bank conflicts) ----
#pragma unroll
    for (int n = 0; n < 8; n++) {
      int c = n * 16 + lrow;
#pragma unroll
      for (int i = 0; i < 4; i++) {
        int lr = lgrp * 4 + i;
        float v = acc1[n][i] - b1v[n];
        v = v > 0.f ? v : 0.f;
        int off = (lr << 8) + (c << 1);
        off ^= (lr & 7) << 4;
        *(unsigned short*)(my_lds + off) = (unsigned short)f2b(v);
      }
    }

    // ---- A2 fragments: k<128 from a (LDS), k in [128,255) from h, k=255 pad ----
    bf16x8 a2[8];
#pragma unroll
    for (int kk = 0; kk < 4; kk++) {
      int k0 = kk * 32 + lgrp * 8;
      int off = (lrow << 8) + (k0 << 1);
      off ^= (lrow & 7) << 4;
      a2[kk] = *(const bf16x8*)(my_lds + off);
    }
    const float* hp = h + (size_t)rc * 127;
#pragma unroll
    for (int kk = 4; kk < 8; kk++) {
      int c0 = (kk - 4) * 32 + lgrp * 8;
      bf16x8 f;
#pragma unroll
      for (int j = 0; j < 8; j++) {
        int c = c0 + j;
        float v = (rok && c < 127) ? hp[c] : 0.f;
        f[j] = f2b(v);
      }
      a2[kk] = f;
    }

    // ---- GEMM2: out_tile[16][256] = cat' @ w2b^T ----
    f32x4 acc2[16];
#pragma unroll
    for (int n = 0; n < 16; n++) acc2[n] = (f32x4){0.f, 0.f, 0.f, 0.f};
#pragma unroll
    for (int kk = 0; kk < 8; kk++) {
#pragma unroll
      for (int n = 0; n < 16; n++) {
        bf16x8 bf = *(const bf16x8*)(w2b + (n * 16 + lrow) * 256 + kk * 32 + lgrp * 8);
        acc2[n] = __builtin_amdgcn_mfma_f32_16x16x32_bf16(a2[kk], bf, acc2[n], 0, 0, 0);
      }
    }

    // ---- store fp32 ----
#pragma unroll
    for (int n = 0; n < 16; n++) {
      int g = n * 16 + lrow;
      if (g < 255) {
#pragma unroll
        for (int i = 0; i < 4; i++) {
          int r2 = rb + lgrp * 4 + i;
          if (r2 < N) out[(size_t)r2 * 255 + g] = acc2[n][i];
        }
      }
    }
  }
}

extern "C" void kernel_launch(void* const* d_in, const int* in_sizes, int n_in,
                              void* d_out, int out_size, void* d_ws, size_t ws_size,
                              hipStream_t stream) {
  const float* h   = (const float*)d_in[0];
  const float* agg = (const float*)d_in[1];
  const float* w1  = (const float*)d_in[2];
  const float* w2  = (const float*)d_in[3];
  float* out = (float*)d_out;
  char* wsb = (char*)d_ws;

  int nelem = in_sizes[1];        // N * 128
  int N = nelem / 128;
  int ntiles = (N + 15) >> 4;

  hipMemsetAsync(d_ws, 0, 1024, stream);                 // zero stats accumulators
  k_stats<<<1024, 256, 0, stream>>>(agg, (float*)wsb, nelem);
  k_finalize<<<1, 128, 0, stream>>>((float*)wsb, 1.0f / (float)N);
  k_prep<<<320, 256, 0, stream>>>(w1, w2, wsb);
  k_main<<<1024, 256, 0, stream>>>(h, agg, wsb, out, N, ntiles);
}